// Round 1
// baseline (133.065 us; speedup 1.0000x reference)
//
#include <hip/hip_runtime.h>
#include <hip/hip_bf16.h>

// Chamfer loss: B=8, P=32, N=M=1024, fp32 inputs, scalar fp32 output.
// Reference quirk: x[bp,m,c] = rp[bp, (3m+c)%M, (3m+c)>>10]  (torch permute+reshape).
// One block per bp pair. 512 threads = 8 waves; wave w handles rows
// m in [w*128, (w+1)*128). Lanes cover all 1024 columns, 16 per lane,
// y held in registers. Row min: shfl_xor butterfly. Col min: per-lane
// registers -> LDS cross-wave merge. Scalar out via one atomicAdd/block.

#define MM 1024
#define NN 1024
#define THREADS 512
#define NWAVES (THREADS / 64)        // 8
#define ROWS_PER_WAVE (MM / NWAVES)  // 128
#define CPL (NN / 64)                // 16 columns per lane

__global__ __launch_bounds__(THREADS, 1)
void chamfer_kernel(const float* __restrict__ nrf,   // (BP, N, 3)  -> y
                    const float* __restrict__ rp,    // (BP, M, 3)  -> x (scrambled view)
                    float* __restrict__ out,         // scalar
                    float inv_bpm, float inv_bpn) {
    const int bp   = blockIdx.x;
    const int tid  = threadIdx.x;
    const int lane = tid & 63;
    const int wave = tid >> 6;

    __shared__ float rpS[MM * 3];             // 12 KB raw copy of rp block
    __shared__ float colminS[NWAVES][NN];     // 32 KB per-wave column-min partials
    __shared__ float rowsumS[NWAVES];
    __shared__ float csumS[NWAVES];

    const float* rpB = rp  + (size_t)bp * MM * 3;
    const float* yB  = nrf + (size_t)bp * NN * 3;

    // Stage rp block into LDS (coalesced).
    #pragma unroll
    for (int i = tid; i < MM * 3; i += THREADS) rpS[i] = rpB[i];

    // Load this lane's 16 y-columns into registers (n = i*64 + lane).
    float y0[CPL], y1[CPL], y2[CPL], yy[CPL], colmin[CPL];
    #pragma unroll
    for (int i = 0; i < CPL; ++i) {
        int n = i * 64 + lane;
        float a = yB[n * 3 + 0];
        float b = yB[n * 3 + 1];
        float c = yB[n * 3 + 2];
        y0[i] = a; y1[i] = b; y2[i] = c;
        yy[i] = a * a + b * b + c * c;
        colmin[i] = 3.4e38f;
    }
    __syncthreads();

    float rowsum = 0.0f;
    const int m0 = wave * ROWS_PER_WAVE;
    for (int r = 0; r < ROWS_PER_WAVE; ++r) {
        const int k = 3 * (m0 + r);
        // scrambled x view (wave-uniform LDS broadcast reads)
        const float x0 = rpS[((k + 0) & (MM - 1)) * 3 + ((k + 0) >> 10)];
        const float x1 = rpS[((k + 1) & (MM - 1)) * 3 + ((k + 1) >> 10)];
        const float x2 = rpS[((k + 2) & (MM - 1)) * 3 + ((k + 2) >> 10)];
        const float xx = x0 * x0 + x1 * x1 + x2 * x2;

        float rmin = 3.4e38f;
        #pragma unroll
        for (int i = 0; i < CPL; ++i) {
            float dot = x0 * y0[i] + x1 * y1[i] + x2 * y2[i];
            float d = __builtin_fmaf(-2.0f, dot, xx + yy[i]);
            rmin = fminf(rmin, d);
            colmin[i] = fminf(colmin[i], d);
        }
        // 64-lane butterfly min -> uniform across wave
        #pragma unroll
        for (int off = 32; off > 0; off >>= 1)
            rmin = fminf(rmin, __shfl_xor(rmin, off, 64));
        rowsum += rmin;
    }

    // Publish per-wave partials.
    #pragma unroll
    for (int i = 0; i < CPL; ++i) colminS[wave][i * 64 + lane] = colmin[i];
    if (lane == 0) rowsumS[wave] = rowsum;
    __syncthreads();

    // Cross-wave column-min merge + sum of column mins.
    float csum = 0.0f;
    for (int n = tid; n < NN; n += THREADS) {
        float cm = colminS[0][n];
        #pragma unroll
        for (int w = 1; w < NWAVES; ++w) cm = fminf(cm, colminS[w][n]);
        csum += cm;
    }
    #pragma unroll
    for (int off = 32; off > 0; off >>= 1)
        csum += __shfl_xor(csum, off, 64);
    if (lane == 0) csumS[wave] = csum;
    __syncthreads();

    if (tid == 0) {
        float rs = 0.0f, cs = 0.0f;
        #pragma unroll
        for (int w = 0; w < NWAVES; ++w) { rs += rowsumS[w]; cs += csumS[w]; }
        atomicAdd(out, rs * inv_bpm + cs * inv_bpn);
    }
}

extern "C" void kernel_launch(void* const* d_in, const int* in_sizes, int n_in,
                              void* d_out, int out_size, void* d_ws, size_t ws_size,
                              hipStream_t stream) {
    const float* nrf = (const float*)d_in[0];  // (B,P,N,3)
    const float* rp  = (const float*)d_in[1];  // (B,P,M,3)
    float* out = (float*)d_out;

    const int BP = in_sizes[1] / (MM * 3);     // 256
    const float inv_bpm = 1.0f / (float)(BP * MM);
    const float inv_bpn = 1.0f / (float)(BP * NN);

    hipMemsetAsync(out, 0, sizeof(float), stream);
    chamfer_kernel<<<BP, THREADS, 0, stream>>>(nrf, rp, out, inv_bpm, inv_bpn);
}

// Round 2
// 98.242 us; speedup vs baseline: 1.3545x; 1.3545x over previous
//
#include <hip/hip_runtime.h>
#include <hip/hip_bf16.h>

// Chamfer loss: B=8, P=32, N=M=1024, fp32 in, scalar fp32 out.
// Reference quirk: x[bp,m,c] = rp[bp, (3m+c)%M, (3m+c)>>10]  (torch permute+reshape).
// One block per bp. 1024 threads = 16 waves (4/SIMD for latency hiding).
// Wave w owns rows [w*64, w*64+64), processed 4 at a time.
// Each lane owns 16 columns (n = i*64+lane); y + colmin live in VGPRs
// (launch_bounds(1024,4) -> 128-VGPR cap, fits ~110 live regs, no AGPR spill).
// Per-row x precomputed once into LDS as (-2x0,-2x1,-2x2,||x||^2); hot loop
// reads it with a single broadcast ds_read_b128.
// rmin reduces over e = yy - 2*x.y (xx added after butterfly); colmin over
// d = e + xx via min trees (v_min3). Scalar out via one atomicAdd per block.

#define MM 1024
#define NN 1024
#define THREADS 1024
#define NWAVES (THREADS / 64)        // 16
#define ROWS_PER_WAVE (MM / NWAVES)  // 64
#define RB 4                         // rows per inner batch
#define CPL (NN / 64)                // 16 columns per lane
#define FINF 3.4e38f

__global__ __launch_bounds__(THREADS, 4)
void chamfer_kernel(const float* __restrict__ nrf,   // (BP, N, 3) -> y
                    const float* __restrict__ rp,    // (BP, M, 3) -> x (scrambled view)
                    float* __restrict__ out,
                    float inv_bpm, float inv_bpn) {
    const int bp   = blockIdx.x;
    const int tid  = threadIdx.x;
    const int lane = tid & 63;
    const int wave = tid >> 6;

    __shared__ float  rpS[MM * 3];            // 12 KB raw rp block
    __shared__ float4 xS[MM];                 // 16 KB per-row (-2x, ||x||^2)
    __shared__ float  colminS[NWAVES][NN];    // 64 KB per-wave column-min partials
    __shared__ float  rowsumS[NWAVES];
    __shared__ float  csumS[NWAVES];

    const float* rpB = rp  + (size_t)bp * MM * 3;
    const float* yB  = nrf + (size_t)bp * NN * 3;

    // Stage rp (coalesced).
    for (int i = tid; i < MM * 3; i += THREADS) rpS[i] = rpB[i];

    // This lane's 16 y-columns into registers.
    float y0[CPL], y1[CPL], y2[CPL], yy[CPL], colmin[CPL];
    #pragma unroll
    for (int i = 0; i < CPL; ++i) {
        int n = i * 64 + lane;
        float a = yB[n * 3 + 0];
        float b = yB[n * 3 + 1];
        float c = yB[n * 3 + 2];
        y0[i] = a; y1[i] = b; y2[i] = c;
        yy[i] = a * a + b * b + c * c;
        colmin[i] = FINF;
    }
    __syncthreads();

    // Precompute per-row x params (one row per thread, scrambled view).
    {
        const int k = 3 * tid;
        float a = rpS[((k + 0) & (MM - 1)) * 3 + ((k + 0) >> 10)];
        float b = rpS[((k + 1) & (MM - 1)) * 3 + ((k + 1) >> 10)];
        float c = rpS[((k + 2) & (MM - 1)) * 3 + ((k + 2) >> 10)];
        xS[tid] = make_float4(-2.0f * a, -2.0f * b, -2.0f * c,
                              a * a + b * b + c * c);
    }
    __syncthreads();

    float rowsum = 0.0f;
    const int m0 = wave * ROWS_PER_WAVE;
    for (int r0 = 0; r0 < ROWS_PER_WAVE; r0 += RB) {
        float4 x[RB];
        #pragma unroll
        for (int j = 0; j < RB; ++j) x[j] = xS[m0 + r0 + j];  // broadcast b128

        float rmin[RB];
        #pragma unroll
        for (int j = 0; j < RB; ++j) rmin[j] = FINF;

        #pragma unroll
        for (int i = 0; i < CPL; ++i) {
            const float a = y0[i], b = y1[i], c = y2[i], s = yy[i];
            float e[RB];
            #pragma unroll
            for (int j = 0; j < RB; ++j) {
                e[j] = __builtin_fmaf(x[j].x, a,
                        __builtin_fmaf(x[j].y, b,
                         __builtin_fmaf(x[j].z, c, s)));
                rmin[j] = fminf(rmin[j], e[j]);
            }
            // colmin over d = e + xx, min-tree (v_min3 friendly)
            float d01 = fminf(e[0] + x[0].w, e[1] + x[1].w);
            float d23 = fminf(e[2] + x[2].w, e[3] + x[3].w);
            colmin[i] = fminf(colmin[i], fminf(d01, d23));
        }

        // 4 interleaved 64-lane butterflies (independent DS chains).
        #pragma unroll
        for (int off = 32; off > 0; off >>= 1) {
            #pragma unroll
            for (int j = 0; j < RB; ++j)
                rmin[j] = fminf(rmin[j], __shfl_xor(rmin[j], off, 64));
        }
        #pragma unroll
        for (int j = 0; j < RB; ++j) rowsum += x[j].w + rmin[j];
    }

    // Publish per-wave partials.
    #pragma unroll
    for (int i = 0; i < CPL; ++i) colminS[wave][i * 64 + lane] = colmin[i];
    if (lane == 0) rowsumS[wave] = rowsum;
    __syncthreads();

    // Cross-wave column-min merge + sum of column mins (1 col per thread).
    {
        const int n = tid;
        float cm = colminS[0][n];
        #pragma unroll
        for (int w = 1; w < NWAVES; ++w) cm = fminf(cm, colminS[w][n]);
        float csum = cm;
        #pragma unroll
        for (int off = 32; off > 0; off >>= 1)
            csum += __shfl_xor(csum, off, 64);
        if (lane == 0) csumS[wave] = csum;
    }
    __syncthreads();

    if (tid == 0) {
        float rs = 0.0f, cs = 0.0f;
        #pragma unroll
        for (int w = 0; w < NWAVES; ++w) { rs += rowsumS[w]; cs += csumS[w]; }
        atomicAdd(out, rs * inv_bpm + cs * inv_bpn);
    }
}

extern "C" void kernel_launch(void* const* d_in, const int* in_sizes, int n_in,
                              void* d_out, int out_size, void* d_ws, size_t ws_size,
                              hipStream_t stream) {
    const float* nrf = (const float*)d_in[0];  // (B,P,N,3)
    const float* rp  = (const float*)d_in[1];  // (B,P,M,3)
    float* out = (float*)d_out;

    const int BP = in_sizes[1] / (MM * 3);     // 256
    const float inv_bpm = 1.0f / (float)(BP * MM);
    const float inv_bpn = 1.0f / (float)(BP * NN);

    hipMemsetAsync(out, 0, sizeof(float), stream);
    chamfer_kernel<<<BP, THREADS, 0, stream>>>(nrf, rp, out, inv_bpm, inv_bpn);
}